// Round 4
// baseline (4760.573 us; speedup 1.0000x reference)
//
#include <hip/hip_runtime.h>
#include <math.h>

#define BATCH 16
#define HID   128
#define NX    128
#define NF    4
#define NT    64
#define MODES 96
#define OM    (5 * HID)        // 640 fused W rows (F + 4*G)
#define XT1   8                // x per S1 block

// ---------------------------------------------------------------------------
// Tables: C[m][x] = cos(2*pi*k_m*x/128), S[m][x] = sin, k_m=(80+m)%128.
// Packed T2[m][x] = {c, s}.
// ---------------------------------------------------------------------------
__global__ void k_tables(float* __restrict__ C, float* __restrict__ S,
                         float2* __restrict__ T2) {
    int m = blockIdx.x;
    int x = threadIdx.x;
    if (x < NX) {
        int k = (80 + m) % NX;
        float ang = (float)((k * x) & (NX - 1)) * (2.0f * (float)M_PI / (float)NX);
        float c = cosf(ang), s = sinf(ang);
        C[m * NX + x] = c;
        S[m * NX + x] = s;
        T2[m * NX + x] = make_float2(c, s);
    }
}

// ---------------------------------------------------------------------------
// dxi[t][b][x][n] = xi[b,n,x,t+1] - xi[b,n,x,t]
// ---------------------------------------------------------------------------
__global__ void k_dxi(const float* __restrict__ xi, float* __restrict__ dxi) {
    int idx = blockIdx.x * blockDim.x + threadIdx.x;
    const int total = (NT - 1) * BATCH * NX * NF;
    if (idx < total) {
        int n = idx & (NF - 1);
        int x = (idx >> 2) & (NX - 1);
        int b = (idx >> 9) & (BATCH - 1);
        int t = idx >> 13;
        const float* base = xi + (((size_t)b * NF + n) * NX + x) * NT;
        dxi[idx] = base[t + 1] - base[t];
    }
}

// ---------------------------------------------------------------------------
// Wt[h][om] with om = g*128 + o; g=0 -> WF[o][h]; g=1..4 -> WG[o][g-1][h]
// ---------------------------------------------------------------------------
__global__ void k_wt(const float* __restrict__ WF, const float* __restrict__ WG,
                     float* __restrict__ Wt) {
    __shared__ float t[32][33];
    int g = blockIdx.z;
    int h0 = blockIdx.x * 32, o0 = blockIdx.y * 32;
    int tx = threadIdx.x, ty = threadIdx.y;
    #pragma unroll
    for (int j = 0; j < 32; j += 8) {
        int o = o0 + ty + j;
        t[ty + j][tx] = (g == 0) ? WF[(size_t)o * HID + h0 + tx]
                                 : WG[((size_t)o * NF + (g - 1)) * HID + h0 + tx];
    }
    __syncthreads();
    #pragma unroll
    for (int j = 0; j < 32; j += 8)
        Wt[(size_t)(h0 + ty + j) * OM + g * HID + o0 + tx] = t[tx][ty + j];
}

// ---------------------------------------------------------------------------
// At2[m][h][o] = {A[0][m][o][h], A[1][m][o][h]}
// ---------------------------------------------------------------------------
__global__ void k_at2(const float* __restrict__ A, float2* __restrict__ At2) {
    __shared__ float t0[32][33], t1[32][33];
    int m = blockIdx.z;
    int h0 = blockIdx.x * 32, o0 = blockIdx.y * 32;
    int tx = threadIdx.x, ty = threadIdx.y;
    const float* A0 = A + (size_t)m * HID * HID;
    const float* A1 = A0 + (size_t)MODES * HID * HID;
    #pragma unroll
    for (int j = 0; j < 32; j += 8) {
        t0[ty + j][tx] = A0[(size_t)(o0 + ty + j) * HID + h0 + tx];
        t1[ty + j][tx] = A1[(size_t)(o0 + ty + j) * HID + h0 + tx];
    }
    __syncthreads();
    #pragma unroll
    for (int j = 0; j < 32; j += 8)
        At2[((size_t)m * HID + h0 + ty + j) * HID + o0 + tx] =
            make_float2(t0[tx][ty + j], t1[tx][ty + j]);
}

// ---------------------------------------------------------------------------
// v0[b][c][m][h]: band-limited shifted FFT of z0 (one-time).
// ---------------------------------------------------------------------------
__global__ __launch_bounds__(256) void k_v0(const float* __restrict__ z0,
                                            const float* __restrict__ C,
                                            const float* __restrict__ S,
                                            float* __restrict__ v) {
    int m = blockIdx.x, b = blockIdx.y;
    int h = threadIdx.x & 127;
    int c = threadIdx.x >> 7;
    const float* zr = z0 + ((size_t)b * HID + h) * NX;
    const float* T  = (c == 0) ? (C + m * NX) : (S + m * NX);
    float acc = 0.f;
    for (int x = 0; x < NX; ++x) acc += zr[x] * T[x];
    if (c) acc = -acc;
    v[(((size_t)b * 2 + c) * MODES + m) * HID + h] = acc;
}

// ---------------------------------------------------------------------------
// S1 (fused IDFT + W-GEMM + tanh/dxi combine). grid (16,16), block 512.
//  A: z[h][x-tile] = (1/128) sum_m (vre*C - vim*S)  -> zs LDS + zstep (+out)
//  B: thread-per-om rows: pre-act[om][x] = sum_h Wt[h][om] zs[h][x]
//     tanh -> Ht LDS; combine: Hc[b][x][o] = Ht[0] + sum_n Ht[1+n]*dxi
// ---------------------------------------------------------------------------
__global__ __launch_bounds__(512) void k_s1(
    const float* __restrict__ v, const float* __restrict__ Ct,
    const float* __restrict__ St, const float* __restrict__ Wt,
    const float* __restrict__ dxi, float* __restrict__ Hc,
    float* __restrict__ zstep, float* __restrict__ out,
    int step, int writeH, int zdirect)
{
    __shared__ float Cs[MODES][XT1];
    __shared__ float Ss[MODES][XT1];
    __shared__ float zs[HID][XT1];      // [h][x] rows 32B
    __shared__ float Ht[5][HID][XT1];   // tanh'd pre-activations
    __shared__ float dxs[XT1][NF];
    int xt = blockIdx.x, b = blockIdx.y;
    int tid = threadIdx.x;
    int xg0 = xt * XT1;

    for (int i = tid; i < MODES * XT1; i += 512) {
        int m = i >> 3, xl = i & 7;
        Cs[m][xl] = Ct[m * NX + xg0 + xl];
        Ss[m][xl] = St[m * NX + xg0 + xl];
    }
    if (writeH && tid < XT1 * NF) {
        int xl = tid >> 2, n = tid & 3;
        dxs[xl][n] = dxi[(((size_t)step * BATCH + b) * NX + xg0 + xl) * NF + n];
    }
    __syncthreads();

    // ---- Phase A ----
    {
        int h = tid & 127, xp = tid >> 7;     // xp 0..3 -> x pair
        int x0 = xp * 2;
        const float* vr = v + ((size_t)b * 2) * MODES * HID + h;
        const float* vi = vr + (size_t)MODES * HID;
        float a0 = 0.f, a1 = 0.f;
        #pragma unroll 4
        for (int m = 0; m < MODES; ++m) {
            float r  = vr[m * HID];
            float im = vi[m * HID];
            float2 c2 = *(const float2*)&Cs[m][x0];
            float2 s2 = *(const float2*)&Ss[m][x0];
            a0 += r * c2.x - im * s2.x;
            a1 += r * c2.y - im * s2.y;
        }
        const float inv = 1.0f / (float)NX;
        a0 *= inv; a1 *= inv;
        *(float2*)&zs[h][x0] = make_float2(a0, a1);   // one-off 16-way ok
        size_t zb = ((size_t)b * NX + xg0 + x0) * HID + h;
        zstep[zb] = a0;
        zstep[zb + HID] = a1;
        if (zdirect) {
            size_t ob = (((size_t)b * HID + h) * NX + xg0 + x0) * NT + step;
            out[ob] = a0; out[ob + NT] = a1;
        }
    }
    __syncthreads();
    if (!writeH) return;

    // ---- Phase B: GEMM rows, W read once per block ----
    {
        float acc0[XT1] = {0,0,0,0,0,0,0,0};
        float acc1[XT1] = {0,0,0,0,0,0,0,0};
        const float* w0 = Wt + tid;            // om = tid
        const float* w1 = Wt + 512 + (tid & 127);
        bool rep1 = (tid < 128);
        #pragma unroll 2
        for (int h = 0; h < HID; ++h) {
            float4 za = *(const float4*)&zs[h][0];  // broadcast b128
            float4 zb4 = *(const float4*)&zs[h][4];
            float w = w0[(size_t)h * OM];
            acc0[0] += w * za.x;  acc0[1] += w * za.y;
            acc0[2] += w * za.z;  acc0[3] += w * za.w;
            acc0[4] += w * zb4.x; acc0[5] += w * zb4.y;
            acc0[6] += w * zb4.z; acc0[7] += w * zb4.w;
            if (rep1) {
                float w2 = w1[(size_t)h * OM];
                acc1[0] += w2 * za.x;  acc1[1] += w2 * za.y;
                acc1[2] += w2 * za.z;  acc1[3] += w2 * za.w;
                acc1[4] += w2 * zb4.x; acc1[5] += w2 * zb4.y;
                acc1[6] += w2 * zb4.z; acc1[7] += w2 * zb4.w;
            }
        }
        {
            int g = tid >> 7, o = tid & 127;
            float4 t0 = make_float4(tanhf(acc0[0]), tanhf(acc0[1]),
                                    tanhf(acc0[2]), tanhf(acc0[3]));
            float4 t1 = make_float4(tanhf(acc0[4]), tanhf(acc0[5]),
                                    tanhf(acc0[6]), tanhf(acc0[7]));
            *(float4*)&Ht[g][o][0] = t0;
            *(float4*)&Ht[g][o][4] = t1;
        }
        if (rep1) {
            int o = tid & 127;
            float4 t0 = make_float4(tanhf(acc1[0]), tanhf(acc1[1]),
                                    tanhf(acc1[2]), tanhf(acc1[3]));
            float4 t1 = make_float4(tanhf(acc1[4]), tanhf(acc1[5]),
                                    tanhf(acc1[6]), tanhf(acc1[7]));
            *(float4*)&Ht[4][o][0] = t0;
            *(float4*)&Ht[4][o][4] = t1;
        }
    }
    __syncthreads();

    // ---- combine + write Hc ----
    {
        int o = tid & 127, xh = tid >> 7;
        #pragma unroll
        for (int j = 0; j < 2; ++j) {
            int x = xh * 2 + j;
            float hv = Ht[0][o][x];
            #pragma unroll
            for (int n = 0; n < NF; ++n)
                hv += Ht[1 + n][o][x] * dxs[x][n];
            Hc[((size_t)b * NX + xg0 + x) * HID + o] = hv;
        }
    }
}

// ---------------------------------------------------------------------------
// S2 (fused DFT + Av + update). grid (8 bq, 96 m), block 256 (o128 x bl2).
//  hf_re = sum_x Hc*C; hf_im = -sum_x Hc*S
//  are = A0 r - A1 i; aim = A1 r - A0 i  (faithful signs)
//  vout = vin + Av + hf  (hf never hits memory)
// ---------------------------------------------------------------------------
__global__ __launch_bounds__(256) void k_s2(
    const float* __restrict__ vin, const float2* __restrict__ At2,
    const float2* __restrict__ T2g, const float* __restrict__ Hc,
    float* __restrict__ vout)
{
    __shared__ float2 vs2[2][HID];
    __shared__ float2 T2s[NX];
    int bq = blockIdx.x, m = blockIdx.y;
    int tid = threadIdx.x;
    int b0 = bq * 2;
    if (tid < NX) T2s[tid] = T2g[(size_t)m * NX + tid];
    if (tid >= NX) {
        int idx = tid - NX;                 // 0..127
        int bl = idx >> 6, hh = (idx & 63) * 2;
        size_t base = (((size_t)(b0 + bl) * 2) * MODES + m) * HID + hh;
        size_t imo = (size_t)MODES * HID;
        vs2[bl][hh]     = make_float2(vin[base],     vin[base + imo]);
        vs2[bl][hh + 1] = make_float2(vin[base + 1], vin[base + 1 + imo]);
    }
    __syncthreads();
    int o = tid & 127, bl = tid >> 7;
    int b = b0 + bl;

    // DFT over x
    const float* hp = Hc + (size_t)b * NX * HID + o;
    float fre = 0.f, fim = 0.f;
    #pragma unroll 4
    for (int x = 0; x < NX; ++x) {
        float hv = hp[(size_t)x * HID];
        float2 t = T2s[x];
        fre += hv * t.x;
        fim -= hv * t.y;
    }
    // Av over h
    const float2* a2 = At2 + (size_t)m * HID * HID + o;
    float are = 0.f, aim = 0.f;
    #pragma unroll 4
    for (int h = 0; h < HID; ++h) {
        float2 a  = a2[(size_t)h * HID];
        float2 vv = vs2[bl][h];
        are += a.x * vv.x - a.y * vv.y;
        aim += a.y * vv.x - a.x * vv.y;
    }
    float2 vo = vs2[bl][o];
    size_t ob = (((size_t)b * 2) * MODES + m) * HID + o;
    vout[ob] = vo.x + are + fre;
    vout[ob + (size_t)MODES * HID] = vo.y + aim + fim;
}

// ---------------------------------------------------------------------------
// Flush: zbuf[tt][b][x][h] (16 steps) -> out[b][h][x][t0+tt]
// ---------------------------------------------------------------------------
__global__ __launch_bounds__(256) void k_flush(const float* __restrict__ zbuf,
                                               float* __restrict__ out, int t0) {
    int x = blockIdx.x, b = blockIdx.y, tid = threadIdx.x;
    __shared__ float tile[16][HID];
    for (int i = tid; i < 16 * HID; i += 256) {
        int tt = i >> 7, h = i & 127;
        tile[tt][h] = zbuf[(((size_t)tt * BATCH + b) * NX + x) * HID + h];
    }
    __syncthreads();
    int h = tid >> 1, half = tid & 1;
    float4 w[2];
    float* wp = (float*)w;
    #pragma unroll
    for (int j = 0; j < 8; ++j) wp[j] = tile[half * 8 + j][h];
    float4* dst = (float4*)(out + (((size_t)b * HID + h) * NX + x) * NT + t0 + half * 8);
    dst[0] = w[0];
    dst[1] = w[1];
}

// ---------------------------------------------------------------------------
extern "C" void kernel_launch(void* const* d_in, const int* in_sizes, int n_in,
                              void* d_out, int out_size, void* d_ws, size_t ws_size,
                              hipStream_t stream) {
    const float* z0 = (const float*)d_in[0];
    const float* xi = (const float*)d_in[1];
    const float* A  = (const float*)d_in[2];
    const float* WF = (const float*)d_in[3];
    const float* WG = (const float*)d_in[4];
    float* out = (float*)d_out;

    float* ws = (float*)d_ws;
    size_t cap = ws_size / sizeof(float);
    size_t off = 0;
    auto alloc = [&](size_t n) { float* p = ws + off; off += n; return p; };

    float*  Ct   = alloc((size_t)MODES * NX);
    float*  St   = alloc((size_t)MODES * NX);
    float2* T2g  = (float2*)alloc((size_t)MODES * NX * 2);
    float*  Wt   = alloc((size_t)HID * OM);
    float2* At2  = (float2*)alloc((size_t)MODES * HID * HID * 2);
    float*  v0b  = alloc((size_t)BATCH * 2 * MODES * HID);
    float*  v1b  = alloc((size_t)BATCH * 2 * MODES * HID);
    float*  Hcb  = alloc((size_t)BATCH * NX * HID);
    float*  dxib = alloc((size_t)(NT - 1) * BATCH * NX * NF);

    const size_t ZSZ = (size_t)BATCH * NX * HID;
    float* zbuf = nullptr;
    if (off + 16 * ZSZ <= cap) zbuf = alloc(16 * ZSZ);
    float* zsingle = nullptr;
    if (!zbuf) zsingle = alloc(ZSZ);
    int zdirect = (zbuf == nullptr) ? 1 : 0;

    // setup
    k_tables<<<MODES, 128, 0, stream>>>(Ct, St, T2g);
    {
        int total = (NT - 1) * BATCH * NX * NF;
        k_dxi<<<(total + 255) / 256, 256, 0, stream>>>(xi, dxib);
    }
    k_wt<<<dim3(4, 4, 5), dim3(32, 8), 0, stream>>>(WF, WG, Wt);
    k_at2<<<dim3(4, 4, MODES), dim3(32, 8), 0, stream>>>(A, At2);
    k_v0<<<dim3(MODES, BATCH), 256, 0, stream>>>(z0, Ct, St, v0b);

    float* vcur = v0b;
    float* vnxt = v1b;
    for (int i = 0; i < NT - 1; ++i) {
        float* zstep = zdirect ? zsingle : (zbuf + (size_t)(i & 15) * ZSZ);
        k_s1<<<dim3(NX / XT1, BATCH), 512, 0, stream>>>(
            vcur, Ct, St, Wt, dxib, Hcb, zstep, out, i, 1, zdirect);
        k_s2<<<dim3(8, MODES), 256, 0, stream>>>(vcur, At2, T2g, Hcb, vnxt);
        float* t = vcur; vcur = vnxt; vnxt = t;
        if (!zdirect && (i & 15) == 15)
            k_flush<<<dim3(NX, BATCH), 256, 0, stream>>>(zbuf, out, i - 15);
    }
    {
        float* zstep = zdirect ? zsingle : (zbuf + (size_t)((NT - 1) & 15) * ZSZ);
        k_s1<<<dim3(NX / XT1, BATCH), 512, 0, stream>>>(
            vcur, Ct, St, Wt, dxib, Hcb, zstep, out, NT - 1, 0, zdirect);
        if (!zdirect)
            k_flush<<<dim3(NX, BATCH), 256, 0, stream>>>(zbuf, out, NT - 16);
    }
}